// Round 1
// baseline (464.944 us; speedup 1.0000x reference)
//
#include <hip/hip_runtime.h>
#include <math.h>

#define TT 8192
#define BB 256
#define EE 8
#define KK 15
#define PI_F  3.14159265358979323846f
#define TPI_F 6.28318530717958647692f

// d_out flat layout (reference tuple order)
#define OFF_OUT 0
#define OFF_LAT (BB*TT)                     // 2097152
#define OFF_SIG (OFF_LAT + BB*EE*TT)        // 18874368
#define OFF_P   (OFF_SIG + BB*EE*TT)        // 35651584
#define OFF_F   (OFF_P + BB*EE)
#define OFF_A   (OFF_F + BB*EE)
#define OFF_B0  (OFF_A + BB*EE)

#define TILE_A 1024
#define TILE_C 1024

// ---------------- Kernel A: dilated per-channel conv stack -> latent ----------------
__global__ __launch_bounds__(256) void conv_stack_kernel(
    const float* __restrict__ x, const float* __restrict__ W1,
    const float* __restrict__ b1, const float* __restrict__ W2,
    const float* __restrict__ b2, float* __restrict__ latent)
{
  __shared__ float sx[TILE_A + 28*128];        // worst case d=128
  __shared__ float sh[2][TILE_A + 14*128];
  const int tile = blockIdx.x, e = blockIdx.y, b = blockIdx.z;
  const int d  = 1 << e;
  const int t0 = tile * TILE_A;
  const int tid = threadIdx.x;
  const int nx = TILE_A + 28*d;
  const int nh = TILE_A + 14*d;
  const float* xr = x + b*TT;

  for (int i = tid; i < nx; i += 256) {
    int t = t0 - 14*d + i;
    sx[i] = (t >= 0 && t < TT) ? xr[t] : 0.0f;
  }

  // uniform weight loads (scalarized by compiler)
  float w1c0[KK], w1c1[KK], w2c0[KK], w2c1[KK];
  #pragma unroll
  for (int k = 0; k < KK; k++) {
    w1c0[k] = W1[e*30 + k];        // W1 (E,2,1,K)
    w1c1[k] = W1[e*30 + 15 + k];
    w2c0[k] = W2[e*30 + k];        // W2 (E,1,2,K)
    w2c1[k] = W2[e*30 + 15 + k];
  }
  float b10 = b1[e*2], b11 = b1[e*2+1], b2v = b2[e];
  __syncthreads();

  // conv1: h_c on extended range [t0-7d, t0+TILE+7d); zero outside [0,T)
  for (int s = tid; s < nh; s += 256) {
    int t = t0 - 7*d + s;
    float a0 = b10, a1 = b11;
    #pragma unroll
    for (int k = 0; k < KK; k++) {
      float xv = sx[s + k*d];
      a0 = fmaf(w1c0[k], xv, a0);
      a1 = fmaf(w1c1[k], xv, a1);
    }
    bool in = (t >= 0 && t < TT);
    sh[0][s] = in ? a0 : 0.0f;     // h is zero-PADDED outside [0,T) for conv2
    sh[1][s] = in ? a1 : 0.0f;
  }
  __syncthreads();

  float* lr = latent + (b*EE + e)*TT + t0;
  for (int u = tid; u < TILE_A; u += 256) {
    float acc = b2v;
    #pragma unroll
    for (int k = 0; k < KK; k++) {
      acc = fmaf(w2c0[k], sh[0][u + k*d], acc);
      acc = fmaf(w2c1[k], sh[1][u + k*d], acc);
    }
    lr[u] = acc;
  }
}

// ---------------- Kernel B: FFT moments + fc phase per (b,e) row ----------------
__global__ __launch_bounds__(512) void fft_kernel(
    const float* __restrict__ latent, const float* __restrict__ fcW,
    const float* __restrict__ fcb, float* __restrict__ outP,
    float* __restrict__ outF, float* __restrict__ outA, float* __restrict__ outB0)
{
  __shared__ float sbuf[2*TT];                 // exactly 64 KB
  float* re = sbuf;
  float* im = sbuf + TT;
  const int e = blockIdx.x, b = blockIdx.y;
  const int tid = threadIdx.x;
  const float* row = latent + (b*EE + e)*TT;
  const float* f0 = fcW + (e*2 + 0)*TT;
  const float* f1 = fcW + (e*2 + 1)*TT;

  double v0 = 0.0, v1 = 0.0;
  for (int j = tid; j < TT; j += 512) {
    float xv = row[j];
    re[j] = xv; im[j] = 0.0f;
    v0 += (double)xv * (double)f0[j];
    v1 += (double)xv * (double)f1[j];
  }
  __syncthreads();

  // in-place radix-2 DIF; output slot j holds X_{bitrev13(j)}
  for (int len = TT >> 1; len >= 1; len >>= 1) {
    float invl = 1.0f / (float)len;
    for (int q = tid; q < (TT >> 1); q += 512) {
      int p  = q & (len - 1);
      int i0 = ((q & ~(len - 1)) << 1) | p;
      int i1 = i0 + len;
      float ur = re[i0], ui = im[i0];
      float vr = re[i1], vi = im[i1];
      re[i0] = ur + vr; im[i0] = ui + vi;
      float dr = ur - vr, di = ui - vi;
      float ang = -PI_F * ((float)p * invl);
      float s, c;
      __sincosf(ang, &s, &c);
      re[i1] = fmaf(dr, c, -di * s);
      im[i1] = fmaf(dr, s,  di * c);
    }
    __syncthreads();
  }

  // spectral moments over full spectrum; double-count k=T/2 (slot j==1), halve at end
  double pacc = 0.0, facc = 0.0;
  for (int j = tid; j < TT; j += 512) {
    unsigned k = __brev((unsigned)j) >> 19;    // bitrev13
    float mr = re[j], mi = im[j];
    float mag = fmaf(mr, mr, mi * mi);
    if (k != 0u) {
      int ki = (int)k;
      int keff = (ki < TT - ki) ? ki : TT - ki;
      float w = (j == 1) ? 2.0f : 1.0f;
      pacc += (double)(w * mag);
      facc += (double)(w * 0.5f * (float)keff * mag);
    }
  }

  #pragma unroll
  for (int off = 32; off > 0; off >>= 1) {
    pacc += __shfl_down(pacc, off);
    facc += __shfl_down(facc, off);
    v0   += __shfl_down(v0, off);
    v1   += __shfl_down(v1, off);
  }
  __syncthreads();                             // everyone done reading im
  int wid = tid >> 6, lane = tid & 63;
  if (lane == 0) {
    im[wid*4 + 0] = (float)pacc;
    im[wid*4 + 1] = (float)facc;
    im[wid*4 + 2] = (float)v0;
    im[wid*4 + 3] = (float)v1;
  }
  __syncthreads();
  if (tid == 0) {
    float P = 0.f, Fw = 0.f, V0 = 0.f, V1 = 0.f;
    #pragma unroll
    for (int w = 0; w < 8; w++) {
      P  += im[w*4 + 0];
      Fw += im[w*4 + 1];
      V0 += im[w*4 + 2];
      V1 += im[w*4 + 3];
    }
    float psum  = 0.5f * P;
    float fmean = Fw / P;                       // (Fw/2)/(P/2)
    float amp   = 2.0f * sqrtf(psum) / (float)TT;
    float boff  = re[0] / (float)TT;            // X_0 (slot 0 natural)
    float vv0 = V0 + fcb[e*2 + 0];
    float vv1 = V1 + fcb[e*2 + 1];
    float ph  = atan2f(vv1, vv0) / TPI_F;
    int idx = b*EE + e;
    outP[idx]  = ph;
    outF[idx]  = fmean;
    outA[idx]  = amp;
    outB0[idx] = boff;
  }
}

// ---------------- Kernel C: sinusoid reconstruction + fused deconv tree ----------------
__global__ __launch_bounds__(256) void sig_deconv_kernel(
    const float* __restrict__ Pv, const float* __restrict__ Fv,
    const float* __restrict__ Av, const float* __restrict__ B0v,
    const float* __restrict__ dW0, const float* __restrict__ db0,
    const float* __restrict__ dW1, const float* __restrict__ db1,
    const float* __restrict__ dW2, const float* __restrict__ db2,
    float* __restrict__ sig, float* __restrict__ out)
{
  __shared__ float ssig[EE][TILE_C + 42];
  __shared__ float sl0[4][TILE_C + 28];
  __shared__ float sl1[2][TILE_C + 14];
  const int tile = blockIdx.x, b = blockIdx.y;
  const int t0 = tile * TILE_C;
  const int tid = threadIdx.x;
  const float step = 2.0f / 8191.0f;            // linspace(-1,1,8192) step

  for (int ch = 0; ch < EE; ch++) {
    int idx = b*EE + ch;
    float fs = Fv[idx], as_ = Av[idx], ps = Pv[idx], bo = B0v[idx];
    float* srow = sig + idx*TT;
    for (int i = tid; i < TILE_C + 42; i += 256) {
      int t = t0 + i - 21;
      float val = 0.0f;
      if (t >= 0 && t < TT) {
        float arg = -1.0f + step * (float)t;
        val = as_ * sinf(TPI_F * fmaf(fs, arg, ps)) + bo;
      }
      ssig[ch][i] = val;
      if (i >= 21 && i < 21 + TILE_C) srow[t] = val;
    }
  }
  __syncthreads();

  // level 0: 8 -> 4 channels (groups=4)
  for (int g = 0; g < 4; g++) {
    float bg = db0[g];
    for (int i = tid; i < TILE_C + 28; i += 256) {
      int t = t0 + i - 14;
      float acc = 0.0f;
      if (t >= 0 && t < TT) {                   // L0 zero-padded outside [0,T)
        acc = bg;
        #pragma unroll
        for (int k = 0; k < KK; k++) {
          acc = fmaf(dW0[g*30 + k],      ssig[2*g    ][i + k], acc);
          acc = fmaf(dW0[g*30 + 15 + k], ssig[2*g + 1][i + k], acc);
        }
      }
      sl0[g][i] = acc;
    }
  }
  __syncthreads();

  // level 1: 4 -> 2 channels (groups=2)
  for (int g = 0; g < 2; g++) {
    float bg = db1[g];
    for (int i = tid; i < TILE_C + 14; i += 256) {
      int t = t0 + i - 7;
      float acc = 0.0f;
      if (t >= 0 && t < TT) {
        acc = bg;
        #pragma unroll
        for (int k = 0; k < KK; k++) {
          acc = fmaf(dW1[g*30 + k],      sl0[2*g    ][i + k], acc);
          acc = fmaf(dW1[g*30 + 15 + k], sl0[2*g + 1][i + k], acc);
        }
      }
      sl1[g][i] = acc;
    }
  }
  __syncthreads();

  // level 2: 2 -> 1 channel
  float* orow = out + b*TT + t0;
  for (int u = tid; u < TILE_C; u += 256) {
    float acc = db2[0];
    #pragma unroll
    for (int k = 0; k < KK; k++) {
      acc = fmaf(dW2[k],      sl1[0][u + k], acc);
      acc = fmaf(dW2[15 + k], sl1[1][u + k], acc);
    }
    orow[u] = acc;
  }
}

extern "C" void kernel_launch(void* const* d_in, const int* in_sizes, int n_in,
                              void* d_out, int out_size, void* d_ws, size_t ws_size,
                              hipStream_t stream) {
  const float* x   = (const float*)d_in[0];
  const float* W1  = (const float*)d_in[1];
  const float* b1  = (const float*)d_in[2];
  const float* W2  = (const float*)d_in[3];
  const float* b2  = (const float*)d_in[4];
  const float* fcW = (const float*)d_in[5];
  const float* fcb = (const float*)d_in[6];
  const float* dW0 = (const float*)d_in[7];
  const float* db0 = (const float*)d_in[8];
  const float* dW1 = (const float*)d_in[9];
  const float* db1 = (const float*)d_in[10];
  const float* dW2 = (const float*)d_in[11];
  const float* db2 = (const float*)d_in[12];

  float* o        = (float*)d_out;
  float* out_main = o + OFF_OUT;
  float* latent   = o + OFF_LAT;
  float* sig      = o + OFF_SIG;
  float* pP  = o + OFF_P;
  float* pF  = o + OFF_F;
  float* pA  = o + OFF_A;
  float* pB0 = o + OFF_B0;

  conv_stack_kernel<<<dim3(TT/TILE_A, EE, BB), 256, 0, stream>>>(x, W1, b1, W2, b2, latent);
  fft_kernel<<<dim3(EE, BB), 512, 0, stream>>>(latent, fcW, fcb, pP, pF, pA, pB0);
  sig_deconv_kernel<<<dim3(TT/TILE_C, BB), 256, 0, stream>>>(
      pP, pF, pA, pB0, dW0, db0, dW1, db1, dW2, db2, sig, out_main);
}